// Round 1
// baseline (25067.584 us; speedup 1.0000x reference)
//
#include <hip/hip_runtime.h>
#include <hip/hip_bf16.h>

#define VOCAB 30522
#define EMB   768
#define HID   1024
#define SEQ   4096
#define NG    4096   // 4*HID gate rows
#define NWG   64     // workgroups in persistent recurrence kernel
#define RT    512    // threads per recurrence workgroup

// w_hh LDS row stride in bytes (1024 bf16 = 2048B + 32B pad -> bank spread, 2-way max)
#define WROW  2080

// ---------------------------------------------------------------------------
// Kernel 1: xg[t][r] = dot(emb[sentence[t]], w_ih[r]) + b_ih[r] + b_hh[r]
// f32 tiled GEMM, output bf16. M=SEQ, N=NG, K=EMB.
// ---------------------------------------------------------------------------
#define BM 64
#define BN 64
#define BK 16

__global__ __launch_bounds__(256) void xg_gemm(
    const int* __restrict__ sent, const float* __restrict__ emb,
    const float* __restrict__ w_ih, const float* __restrict__ b_ih,
    const float* __restrict__ b_hh, __hip_bfloat16* __restrict__ xg) {
  __shared__ float As[BK][BM + 4];
  __shared__ float Bs[BK][BN + 4];
  const int tid = threadIdx.x;
  const int n0 = blockIdx.x * BN;
  const int m0 = blockIdx.y * BM;
  const int tx = tid & 15, ty = tid >> 4;       // 16 x 16 thread grid, 4x4 per thread
  const int lr = tid >> 2;                      // 0..63 tile row for loading
  const int lk = (tid & 3) * 4;                 // 0,4,8,12 k-offset for loading

  const int arow = sent[m0 + lr];
  const float* aptr = emb + (size_t)arow * EMB + lk;
  const float* bptr = w_ih + (size_t)(n0 + lr) * EMB + lk;

  float acc[4][4] = {};

  for (int k0 = 0; k0 < EMB; k0 += BK) {
    float4 av = *(const float4*)(aptr + k0);
    float4 bv = *(const float4*)(bptr + k0);
    __syncthreads();
    As[lk + 0][lr] = av.x; As[lk + 1][lr] = av.y;
    As[lk + 2][lr] = av.z; As[lk + 3][lr] = av.w;
    Bs[lk + 0][lr] = bv.x; Bs[lk + 1][lr] = bv.y;
    Bs[lk + 2][lr] = bv.z; Bs[lk + 3][lr] = bv.w;
    __syncthreads();
#pragma unroll
    for (int k = 0; k < BK; ++k) {
      float4 a = *(const float4*)&As[k][ty * 4];
      float4 b = *(const float4*)&Bs[k][tx * 4];
      acc[0][0] = fmaf(a.x, b.x, acc[0][0]); acc[0][1] = fmaf(a.x, b.y, acc[0][1]);
      acc[0][2] = fmaf(a.x, b.z, acc[0][2]); acc[0][3] = fmaf(a.x, b.w, acc[0][3]);
      acc[1][0] = fmaf(a.y, b.x, acc[1][0]); acc[1][1] = fmaf(a.y, b.y, acc[1][1]);
      acc[1][2] = fmaf(a.y, b.z, acc[1][2]); acc[1][3] = fmaf(a.y, b.w, acc[1][3]);
      acc[2][0] = fmaf(a.z, b.x, acc[2][0]); acc[2][1] = fmaf(a.z, b.y, acc[2][1]);
      acc[2][2] = fmaf(a.z, b.z, acc[2][2]); acc[2][3] = fmaf(a.z, b.w, acc[2][3]);
      acc[3][0] = fmaf(a.w, b.x, acc[3][0]); acc[3][1] = fmaf(a.w, b.y, acc[3][1]);
      acc[3][2] = fmaf(a.w, b.z, acc[3][2]); acc[3][3] = fmaf(a.w, b.w, acc[3][3]);
    }
  }

#pragma unroll
  for (int i = 0; i < 4; ++i) {
    int gm = m0 + ty * 4 + i;
#pragma unroll
    for (int j = 0; j < 4; ++j) {
      int gn = n0 + tx * 4 + j;
      float v = acc[i][j] + b_ih[gn] + b_hh[gn];
      xg[(size_t)gm * NG + gn] = __float2bfloat16(v);
    }
  }
}

// ---------------------------------------------------------------------------
// Kernel 2: persistent LSTM recurrence. 64 WGs, each owns 16 h-indices
// (64 gate rows). w_hh slice in LDS as bf16. Device-wide barrier per step
// via agent-scope atomics (h published with relaxed atomic stores + release
// counter add; readers acquire).
// ---------------------------------------------------------------------------
__global__ __launch_bounds__(RT, 2) void lstm_rec(
    const float* __restrict__ w_hh, const __hip_bfloat16* __restrict__ xg,
    float* __restrict__ h_buf, int* __restrict__ counter) {
  extern __shared__ char smem[];
  float* h_lds  = (float*)(smem + 64 * WROW);   // 1024 f32
  float* xg_b   = h_lds + HID;                  // 64
  float* gate_b = xg_b + 64;                    // 64
  float* c_b    = gate_b + 64;                  // 16

  const int wg = blockIdx.x;
  const int tid = threadIdx.x;

  // Stage this WG's w_hh slice into LDS as bf16.
  // local row rl (0..63) <-> global gate row (rl>>4)*1024 + wg*16 + (rl&15)
  for (int i = tid; i < 64 * 1024; i += RT) {
    int rl = i >> 10, k = i & 1023;
    int gr = ((rl >> 4) << 10) + wg * 16 + (rl & 15);
    float v = w_hh[(size_t)gr * HID + k];
    *((__hip_bfloat16*)(smem + rl * WROW) + k) = __float2bfloat16(v);
  }
  if (tid < 16) c_b[tid] = 0.f;
  __syncthreads();

  // dot-product lane mapping: wave wv -> gate q = wv>>1, half = wv&1
  // within wave: 8 rows (lane>>3), 8 chunks (lane&7); each lane: 64 bf16 pairs
  const int wv = tid >> 6, lane = tid & 63;
  const int q = wv >> 1, half = wv & 1;
  const int rr = lane >> 3, cc = lane & 7;
  const int rl = q * 16 + half * 8 + rr;
  const char* wrow = smem + rl * WROW;
  const int gidx = q * 16 + half * 8 + rr;      // index into gate_b / xg_b

  for (int t = 0; t < SEQ; ++t) {
    // stage h_{t-1} (global, agent-coherent) into LDS
    const float* hs = h_buf + (((t + 1) & 1) << 10);
    float a0 = __hip_atomic_load(hs + tid * 2,     __ATOMIC_RELAXED, __HIP_MEMORY_SCOPE_AGENT);
    float a1 = __hip_atomic_load(hs + tid * 2 + 1, __ATOMIC_RELAXED, __HIP_MEMORY_SCOPE_AGENT);
    h_lds[tid * 2]     = a0;
    h_lds[tid * 2 + 1] = a1;
    if (tid < 64) {
      int gr = ((tid >> 4) << 10) + wg * 16 + (tid & 15);
      xg_b[tid] = __bfloat162float(xg[(size_t)t * NG + gr]);
    }
    __syncthreads();

    float acc = 0.f;
#pragma unroll 16
    for (int j = 0; j < 64; ++j) {
      int p = cc + (j << 3);                            // bf16-pair index
      unsigned wp = *(const unsigned*)(wrow + p * 4);   // 2 bf16 weights
      float2 hv = *(const float2*)(h_lds + p * 2);
      acc = fmaf(__uint_as_float(wp << 16),        hv.x, acc);
      acc = fmaf(__uint_as_float(wp & 0xffff0000u), hv.y, acc);
    }
    acc += __shfl_down(acc, 4, 8);
    acc += __shfl_down(acc, 2, 8);
    acc += __shfl_down(acc, 1, 8);
    if (cc == 0) gate_b[gidx] = acc + xg_b[gidx];
    __syncthreads();

    if (tid < 16) {
      float gi = gate_b[tid], gf = gate_b[16 + tid];
      float gg = gate_b[32 + tid], go = gate_b[48 + tid];
      float i_ = 1.f / (1.f + expf(-gi));
      float f_ = 1.f / (1.f + expf(-gf));
      float g_ = tanhf(gg);
      float o_ = 1.f / (1.f + expf(-go));
      float cn = fmaf(f_, c_b[tid], i_ * g_);
      c_b[tid] = cn;
      float hn = o_ * tanhf(cn);
      __hip_atomic_store(h_buf + ((t & 1) << 10) + wg * 16 + tid, hn,
                         __ATOMIC_RELAXED, __HIP_MEMORY_SCOPE_AGENT);
    }
    __syncthreads();
    if (tid == 0) {
      __hip_atomic_fetch_add(counter, 1, __ATOMIC_RELEASE, __HIP_MEMORY_SCOPE_AGENT);
      const int target = (t + 1) * NWG;
      while (__hip_atomic_load(counter, __ATOMIC_ACQUIRE, __HIP_MEMORY_SCOPE_AGENT) < target) {
        __builtin_amdgcn_s_sleep(1);
      }
    }
    __syncthreads();
  }
}

// ---------------------------------------------------------------------------
// Kernel 3: y = h_T @ w_out.T + b_out ; log_softmax
// ---------------------------------------------------------------------------
__global__ __launch_bounds__(256) void head_kernel(
    const float* __restrict__ h, const float* __restrict__ w_out,
    const float* __restrict__ b_out, float* __restrict__ out) {
  __shared__ float s0[256], s1[256];
  const int tid = threadIdx.x;
  float p0 = 0.f, p1 = 0.f;
  for (int i = tid; i < HID; i += 256) {
    float hv = h[i];
    p0 = fmaf(hv, w_out[i], p0);
    p1 = fmaf(hv, w_out[HID + i], p1);
  }
  s0[tid] = p0; s1[tid] = p1;
  __syncthreads();
  for (int off = 128; off; off >>= 1) {
    if (tid < off) { s0[tid] += s0[tid + off]; s1[tid] += s1[tid + off]; }
    __syncthreads();
  }
  if (tid == 0) {
    float y0 = s0[0] + b_out[0], y1 = s1[0] + b_out[1];
    float m = fmaxf(y0, y1);
    float lse = m + logf(expf(y0 - m) + expf(y1 - m));
    out[0] = y0 - lse;
    out[1] = y1 - lse;
  }
}

// ---------------------------------------------------------------------------
extern "C" void kernel_launch(void* const* d_in, const int* in_sizes, int n_in,
                              void* d_out, int out_size, void* d_ws, size_t ws_size,
                              hipStream_t stream) {
  const int*   sent  = (const int*)d_in[0];
  const float* emb   = (const float*)d_in[1];
  const float* w_ih  = (const float*)d_in[2];
  const float* w_hh  = (const float*)d_in[3];
  const float* b_ih  = (const float*)d_in[4];
  const float* b_hh  = (const float*)d_in[5];
  const float* w_out = (const float*)d_in[6];
  const float* b_out = (const float*)d_in[7];
  float* out = (float*)d_out;

  // workspace layout
  int*   counter = (int*)d_ws;                                   // offset 0
  float* h_buf   = (float*)((char*)d_ws + 256);                  // 2*1024 f32
  __hip_bfloat16* xg = (__hip_bfloat16*)((char*)d_ws + 16384);   // SEQ*NG bf16

  // zero counter + h double-buffer (required fresh every launch/replay)
  hipMemsetAsync(d_ws, 0, 16384, stream);

  // xg GEMM
  dim3 ggrid(NG / BN, SEQ / BM);
  xg_gemm<<<ggrid, 256, 0, stream>>>(sent, emb, w_ih, b_ih, b_hh, xg);

  // persistent recurrence
  const size_t smem_bytes = 64 * WROW + (HID + 64 + 64 + 16) * sizeof(float);
  hipFuncSetAttribute((const void*)lstm_rec,
                      hipFuncAttributeMaxDynamicSharedMemorySize,
                      (int)smem_bytes);
  lstm_rec<<<NWG, RT, smem_bytes, stream>>>(w_hh, xg, h_buf, counter);

  // head: final h is in buffer (4095 & 1) == 1
  head_kernel<<<1, 256, 0, stream>>>(h_buf + HID, w_out, b_out, out);
}

// Round 2
// 15670.132 us; speedup vs baseline: 1.5997x; 1.5997x over previous
//
#include <hip/hip_runtime.h>
#include <hip/hip_bf16.h>

#define VOCAB 30522
#define EMB   768
#define HID   1024
#define SEQ   4096
#define NG    4096   // 4*HID gate rows
#define NWG   64     // workgroups in persistent recurrence kernel
#define RT    512    // threads per recurrence workgroup

// ---------------------------------------------------------------------------
// Kernel 1: xg[t][r] = dot(emb[sentence[t]], w_ih[r]) + b_ih[r] + b_hh[r]
// f32 tiled GEMM, output bf16. M=SEQ, N=NG, K=EMB.
// ---------------------------------------------------------------------------
#define BM 64
#define BN 64
#define BK 16

__global__ __launch_bounds__(256) void xg_gemm(
    const int* __restrict__ sent, const float* __restrict__ emb,
    const float* __restrict__ w_ih, const float* __restrict__ b_ih,
    const float* __restrict__ b_hh, __hip_bfloat16* __restrict__ xg) {
  __shared__ float As[BK][BM + 4];
  __shared__ float Bs[BK][BN + 4];
  const int tid = threadIdx.x;
  const int n0 = blockIdx.x * BN;
  const int m0 = blockIdx.y * BM;
  const int tx = tid & 15, ty = tid >> 4;       // 16 x 16 thread grid, 4x4 per thread
  const int lr = tid >> 2;                      // 0..63 tile row for loading
  const int lk = (tid & 3) * 4;                 // 0,4,8,12 k-offset for loading

  const int arow = sent[m0 + lr];
  const float* aptr = emb + (size_t)arow * EMB + lk;
  const float* bptr = w_ih + (size_t)(n0 + lr) * EMB + lk;

  float acc[4][4] = {};

  for (int k0 = 0; k0 < EMB; k0 += BK) {
    float4 av = *(const float4*)(aptr + k0);
    float4 bv = *(const float4*)(bptr + k0);
    __syncthreads();
    As[lk + 0][lr] = av.x; As[lk + 1][lr] = av.y;
    As[lk + 2][lr] = av.z; As[lk + 3][lr] = av.w;
    Bs[lk + 0][lr] = bv.x; Bs[lk + 1][lr] = bv.y;
    Bs[lk + 2][lr] = bv.z; Bs[lk + 3][lr] = bv.w;
    __syncthreads();
#pragma unroll
    for (int k = 0; k < BK; ++k) {
      float4 a = *(const float4*)&As[k][ty * 4];
      float4 b = *(const float4*)&Bs[k][tx * 4];
      acc[0][0] = fmaf(a.x, b.x, acc[0][0]); acc[0][1] = fmaf(a.x, b.y, acc[0][1]);
      acc[0][2] = fmaf(a.x, b.z, acc[0][2]); acc[0][3] = fmaf(a.x, b.w, acc[0][3]);
      acc[1][0] = fmaf(a.y, b.x, acc[1][0]); acc[1][1] = fmaf(a.y, b.y, acc[1][1]);
      acc[1][2] = fmaf(a.y, b.z, acc[1][2]); acc[1][3] = fmaf(a.y, b.w, acc[1][3]);
      acc[2][0] = fmaf(a.z, b.x, acc[2][0]); acc[2][1] = fmaf(a.z, b.y, acc[2][1]);
      acc[2][2] = fmaf(a.z, b.z, acc[2][2]); acc[2][3] = fmaf(a.z, b.w, acc[2][3]);
      acc[3][0] = fmaf(a.w, b.x, acc[3][0]); acc[3][1] = fmaf(a.w, b.y, acc[3][1]);
      acc[3][2] = fmaf(a.w, b.z, acc[3][2]); acc[3][3] = fmaf(a.w, b.w, acc[3][3]);
    }
  }

#pragma unroll
  for (int i = 0; i < 4; ++i) {
    int gm = m0 + ty * 4 + i;
#pragma unroll
    for (int j = 0; j < 4; ++j) {
      int gn = n0 + tx * 4 + j;
      float v = acc[i][j] + b_ih[gn] + b_hh[gn];
      xg[(size_t)gm * NG + gn] = __float2bfloat16(v);
    }
  }
}

// ---------------------------------------------------------------------------
// Kernel 2: persistent LSTM recurrence, tag-in-word sync (no fences).
// 64 WGs x 512 threads. Wave wv owns h-indices {16*wg+2*wv, +1} (8 gate rows).
// w_hh rows live in f32 VGPRs (128 regs/thread). h published as
// (epoch<<32 | float_bits) 8B relaxed agent atomics, double-buffered.
// Readers poll their own 2 slots (tag==t), stage to LDS, one barrier, dot.
// Safety: a producer can only overwrite slot@t with tag t+2 after consuming
// all tag-(t+1) slots, which requires every WG to have fully staged tag t.
// ---------------------------------------------------------------------------
__global__ __launch_bounds__(RT, 2) void lstm_rec(
    const float* __restrict__ w_hh, const __hip_bfloat16* __restrict__ xg,
    unsigned long long* __restrict__ slots) {
  __shared__ float2 hl[2][512];

  const int tid  = threadIdx.x;
  const int wg   = blockIdx.x;
  const int lane = tid & 63;
  const int wv   = tid >> 6;     // wave 0..7
  const int rg   = lane >> 3;    // row-group 0..7
  const int q    = rg >> 1;      // gate 0..3 (i,f,g,o)
  const int mo   = rg & 1;       // which of the wave's 2 h-indices
  const int cc   = lane & 7;     // k-chunk 0..7
  const int hi   = wg * 16 + wv * 2 + mo;   // owned h index
  const int r    = q * HID + hi;            // gate row in [0,4096)

  // --- load this lane's 128 w_hh weights into VGPRs (f32, exact) ---
  float2 w[64];
  const float* wr = w_hh + (size_t)r * HID;
#pragma unroll
  for (int j = 0; j < 64; ++j)
    w[j] = *(const float2*)(wr + 2 * (cc + 8 * j));

  float c = 0.f;
  const int s0 = 2 * tid, s1 = 2 * tid + 1;

  for (int t = 0; t < SEQ; ++t) {
    // prefetch xg for my row (latency hides under the poll)
    float xgv = __bfloat162float(xg[(size_t)t * NG + r]);

    // poll my 2 slots until tag == t, then stage into LDS
    const unsigned long long want = (unsigned long long)t;
    unsigned long long* sb = slots + ((t & 1) << 10);
    unsigned long long v0, v1;
    for (;;) {
      v0 = __hip_atomic_load(sb + s0, __ATOMIC_RELAXED, __HIP_MEMORY_SCOPE_AGENT);
      v1 = __hip_atomic_load(sb + s1, __ATOMIC_RELAXED, __HIP_MEMORY_SCOPE_AGENT);
      if ((v0 >> 32) == want && (v1 >> 32) == want) break;
      __builtin_amdgcn_s_sleep(1);
    }
    hl[t & 1][tid] = make_float2(__uint_as_float((unsigned)v0),
                                 __uint_as_float((unsigned)v1));
    __syncthreads();

    // dot: row r x h, K split 8 ways (cc), pairs p = cc + 8j
    const float2* hb = hl[t & 1];
    float acc = 0.f;
#pragma unroll
    for (int j = 0; j < 64; ++j) {
      float2 h2 = hb[cc + 8 * j];
      acc = fmaf(w[j].x, h2.x, acc);
      acc = fmaf(w[j].y, h2.y, acc);
    }
    // reduce over cc within each 8-lane row group
    acc += __shfl_down(acc, 4, 8);
    acc += __shfl_down(acc, 2, 8);
    acc += __shfl_down(acc, 1, 8);
    acc += xgv;   // cc==0 lanes now hold the full gate pre-activation

    // gather f,g,o gates to the i-gate lanes (0 -> mo=0, 8 -> mo=1)
    float vf = __shfl(acc, (lane & 8) + 16);
    float vg = __shfl(acc, (lane & 8) + 32);
    float vo = __shfl(acc, (lane & 8) + 48);

    if ((lane & 55) == 0) {   // lanes 0 and 8 only
      float i_ = 1.f / (1.f + __expf(-acc));
      float f_ = 1.f / (1.f + __expf(-vf));
      float g_ = tanhf(vg);
      float o_ = 1.f / (1.f + __expf(-vo));
      c = fmaf(f_, c, i_ * g_);
      float hn = o_ * tanhf(c);
      unsigned long long pv =
          ((unsigned long long)(unsigned)(t + 1) << 32) | (unsigned long long)__float_as_uint(hn);
      __hip_atomic_store(slots + (((t + 1) & 1) << 10) + hi, pv,
                         __ATOMIC_RELAXED, __HIP_MEMORY_SCOPE_AGENT);
    }
    // no trailing barrier: next staging targets the other LDS buffer, and
    // tag t+2 can only appear after every WG fully consumed tag t.
  }
}

// ---------------------------------------------------------------------------
// Kernel 3: y = h_T @ w_out.T + b_out ; log_softmax. h_T = slots buf0 values.
// ---------------------------------------------------------------------------
__global__ __launch_bounds__(256) void head_kernel(
    const unsigned long long* __restrict__ hslots, const float* __restrict__ w_out,
    const float* __restrict__ b_out, float* __restrict__ out) {
  __shared__ float s0[256], s1[256];
  const int tid = threadIdx.x;
  float p0 = 0.f, p1 = 0.f;
  for (int i = tid; i < HID; i += 256) {
    float hv = __uint_as_float((unsigned)hslots[i]);
    p0 = fmaf(hv, w_out[i], p0);
    p1 = fmaf(hv, w_out[HID + i], p1);
  }
  s0[tid] = p0; s1[tid] = p1;
  __syncthreads();
  for (int off = 128; off; off >>= 1) {
    if (tid < off) { s0[tid] += s0[tid + off]; s1[tid] += s1[tid + off]; }
    __syncthreads();
  }
  if (tid == 0) {
    float y0 = s0[0] + b_out[0], y1 = s1[0] + b_out[1];
    float m = fmaxf(y0, y1);
    float lse = m + logf(expf(y0 - m) + expf(y1 - m));
    out[0] = y0 - lse;
    out[1] = y1 - lse;
  }
}

// ---------------------------------------------------------------------------
extern "C" void kernel_launch(void* const* d_in, const int* in_sizes, int n_in,
                              void* d_out, int out_size, void* d_ws, size_t ws_size,
                              hipStream_t stream) {
  const int*   sent  = (const int*)d_in[0];
  const float* emb   = (const float*)d_in[1];
  const float* w_ih  = (const float*)d_in[2];
  const float* w_hh  = (const float*)d_in[3];
  const float* b_ih  = (const float*)d_in[4];
  const float* b_hh  = (const float*)d_in[5];
  const float* w_out = (const float*)d_in[6];
  const float* b_out = (const float*)d_in[7];
  float* out = (float*)d_out;

  // workspace layout
  unsigned long long* slots = (unsigned long long*)d_ws;         // 2*1024*8 = 16KB
  __hip_bfloat16* xg = (__hip_bfloat16*)((char*)d_ws + 16384);   // SEQ*NG bf16

  // zero slot tags (= h_0 state at epoch 0) every launch/replay
  hipMemsetAsync(d_ws, 0, 16384, stream);

  // xg GEMM
  dim3 ggrid(NG / BN, SEQ / BM);
  xg_gemm<<<ggrid, 256, 0, stream>>>(sent, emb, w_ih, b_ih, b_hh, xg);

  // persistent recurrence (64 blocks << 256 CUs -> always co-resident)
  lstm_rec<<<NWG, RT, 0, stream>>>(w_hh, xg, slots);

  // head: final h tagged 4096 lives in slots buffer 0
  head_kernel<<<1, 256, 0, stream>>>(slots, w_out, b_out, out);
}